// Round 4
// baseline (303.536 us; speedup 1.0000x reference)
//
#include <hip/hip_runtime.h>
#include <cstdint>

// Problem sizes (fixed by reference)
#define S_    2048
#define DM    1024
#define DH    4096
#define NTOK  8192     // B*S = 4*2048
#define WELEM 4194304  // 4096*1024 elements in each weight matrix
#define CT    8        // tokens per conv block

typedef int v4i __attribute__((ext_vector_type(4)));

// async global->LDS, 16B per lane, dest = ldsbase + lane*16 (wave-uniform base)
#define GLOAD_LDS16(g, l)                                                   \
    __builtin_amdgcn_global_load_lds(                                       \
        (const __attribute__((address_space(1))) void*)(g),                 \
        (__attribute__((address_space(3))) void*)(l), 16, 0, 0)

// ---------------------------------------------------------------------------
// Per-block partial sums of |w| in fp64, both matrices in one launch.
// Blocks [0,1024) -> w1, [1024,2048) -> w2. Deterministic fixed mapping.
__global__ __launch_bounds__(256) void absmean_partial(const float4* __restrict__ wa,
                                                       const float4* __restrict__ wb,
                                                       double* __restrict__ partial) {
    __shared__ double red[256];
    const float4* w = (blockIdx.x < 1024) ? wa : wb;
    int base = (blockIdx.x & 1023) * 1024;  // in float4 units
    double s = 0.0;
#pragma unroll
    for (int k = 0; k < 4; ++k) {
        float4 v = w[base + (k << 8) + threadIdx.x];
        s += (double)fabsf(v.x) + (double)fabsf(v.y) +
             (double)fabsf(v.z) + (double)fabsf(v.w);
    }
    red[threadIdx.x] = s;
    __syncthreads();
    for (int off = 128; off > 0; off >>= 1) {
        if (threadIdx.x < off) red[threadIdx.x] += red[threadIdx.x + off];
        __syncthreads();
    }
    if (threadIdx.x == 0) partial[blockIdx.x] = red[0];
}

// Deterministic tree-sum of partials; scale = 1/clip(mean,1e-5) fp32.
__global__ __launch_bounds__(256) void finalize_scales(const double* __restrict__ part,
                                                       float* __restrict__ sc) {
    __shared__ double red[1024];
#pragma unroll 1
    for (int m = 0; m < 2; ++m) {
        const double* p = part + m * 1024;
        __syncthreads();
#pragma unroll
        for (int k = 0; k < 4; ++k) red[(k << 8) + threadIdx.x] = p[(k << 8) + threadIdx.x];
        __syncthreads();
        double s = red[threadIdx.x] + red[threadIdx.x + 256] +
                   red[threadIdx.x + 512] + red[threadIdx.x + 768];
        __syncthreads();
        red[threadIdx.x] = s;
        __syncthreads();
        for (int off = 128; off > 0; off >>= 1) {
            if (threadIdx.x < off) red[threadIdx.x] += red[threadIdx.x + off];
            __syncthreads();
        }
        if (threadIdx.x == 0) {
            double mean = red[0] / (double)WELEM;
            float mf = fmaxf((float)mean, 1e-5f);
            float scale = 1.0f / mf;
            sc[2 * m]     = scale;
            sc[2 * m + 1] = 1.0f / scale;
        }
    }
}

// Ternary-quantize both weight matrices in one launch:
// blocks [0,4096) -> w1 (slot 0), [4096,8192) -> w2 (slot 2).
__global__ __launch_bounds__(256) void quant_w(const float4* __restrict__ wa,
                                               const float4* __restrict__ wb,
                                               char4* __restrict__ qa,
                                               char4* __restrict__ qb,
                                               const float* __restrict__ sc) {
    bool second = blockIdx.x >= 4096;
    const float4* w = second ? wb : wa;
    char4* q = second ? qb : qa;
    float scale = sc[second ? 2 : 0];
    int i = (blockIdx.x & 4095) * 256 + threadIdx.x;
    float4 v = w[i];
    char4 o;
    o.x = (signed char)(int)fminf(fmaxf(rintf(v.x * scale), -1.f), 1.f);
    o.y = (signed char)(int)fminf(fmaxf(rintf(v.y * scale), -1.f), 1.f);
    o.z = (signed char)(int)fminf(fmaxf(rintf(v.z * scale), -1.f), 1.f);
    o.w = (signed char)(int)fminf(fmaxf(rintf(v.w * scale), -1.f), 1.f);
    q[i] = o;
}

// Per-token int8 absmax quantization of x (row length DM=1024), float4 loads
__global__ __launch_bounds__(256) void quant_x_kernel(const float4* __restrict__ x,
                                                      char4* __restrict__ q,
                                                      float* __restrict__ dq) {
    __shared__ float red[256];
    int t = blockIdx.x;
    float4 v = x[(size_t)t * 256 + threadIdx.x];
    float mx = fmaxf(fmaxf(fabsf(v.x), fabsf(v.y)), fmaxf(fabsf(v.z), fabsf(v.w)));
    red[threadIdx.x] = mx;
    __syncthreads();
    for (int off = 128; off > 0; off >>= 1) {
        if (threadIdx.x < off) red[threadIdx.x] = fmaxf(red[threadIdx.x], red[threadIdx.x + off]);
        __syncthreads();
    }
    float scale = 127.0f / fmaxf(red[0], 1e-5f);
    char4 o;
    o.x = (signed char)(int)fminf(fmaxf(rintf(v.x * scale), -128.f), 127.f);
    o.y = (signed char)(int)fminf(fmaxf(rintf(v.y * scale), -128.f), 127.f);
    o.z = (signed char)(int)fminf(fmaxf(rintf(v.z * scale), -128.f), 127.f);
    o.w = (signed char)(int)fminf(fmaxf(rintf(v.w * scale), -128.f), 127.f);
    q[(size_t)t * 256 + threadIdx.x] = o;
    if (threadIdx.x == 0) dq[t] = 1.0f / scale;
}

// Fused depthwise conv3 (+bias) + SiLU + per-token int8 quant over DH=4096.
// Register sliding window along t: 512 threads each own 8 channels (2 float4),
// rows prev/cur/next live in registers, row t+2 prefetched before the max
// reduction so its latency overlaps reduce+quant+store. One barrier per row
// (ping-pong red buffer). h is read exactly once.
__global__ __launch_bounds__(512) void conv_silu_quant(const float4* __restrict__ h,
                                                       const float4* __restrict__ cw,
                                                       const float4* __restrict__ cb,
                                                       char4* __restrict__ q,
                                                       float* __restrict__ dq) {
    __shared__ float red[2][8];
    const int tid = threadIdx.x;
    const int t0 = blockIdx.x * CT;
    const int s0 = t0 & (S_ - 1);      // CT | S_, block never straddles batches

    float4 w0[2], w1[2], w2[2], bb[2];
#pragma unroll
    for (int k = 0; k < 2; ++k) {
        int g = (k << 9) + tid;
        w0[k] = cw[3 * g]; w1[k] = cw[3 * g + 1]; w2[k] = cw[3 * g + 2];
        bb[k] = cb[g];
    }

    const float4 z4 = {0.f, 0.f, 0.f, 0.f};
    float4 pv[2], cu[2], nx[2], pf[2];
#pragma unroll
    for (int k = 0; k < 2; ++k) {
        int g = (k << 9) + tid;
        pv[k] = (s0 > 0) ? h[(size_t)(t0 - 1) * 1024 + g] : z4;
        cu[k] = h[(size_t)t0 * 1024 + g];
        nx[k] = h[(size_t)(t0 + 1) * 1024 + g];  // s0+1 < S_ always (CT|S_, t0 row exists)
    }

#pragma unroll
    for (int i = 0; i < CT; ++i) {
        const int t = t0 + i;
        // prefetch row t+2 (zeros past sequence end; never past array end)
        bool hp2 = (s0 + i + 2) < S_;
#pragma unroll
        for (int k = 0; k < 2; ++k)
            pf[k] = hp2 ? h[(size_t)(t + 2) * 1024 + (k << 9) + tid] : z4;

        float4 v[2];
        float mx = 0.f;
#pragma unroll
        for (int k = 0; k < 2; ++k) {
            float4 a = pv[k], b = cu[k], c = nx[k];
            float4 y;
            y.x = w0[k].x * a.x + w0[k].y * b.x + w0[k].z * c.x + bb[k].x;
            y.y = w0[k].w * a.y + w1[k].x * b.y + w1[k].y * c.y + bb[k].y;
            y.z = w1[k].z * a.z + w1[k].w * b.z + w2[k].x * c.z + bb[k].z;
            y.w = w2[k].y * a.w + w2[k].z * b.w + w2[k].w * c.w + bb[k].w;
            float4 r;
            r.x = y.x / (1.0f + expf(-y.x));
            r.y = y.y / (1.0f + expf(-y.y));
            r.z = y.z / (1.0f + expf(-y.z));
            r.w = y.w / (1.0f + expf(-y.w));
            v[k] = r;
            mx = fmaxf(mx, fmaxf(fmaxf(fabsf(r.x), fabsf(r.y)), fmaxf(fabsf(r.z), fabsf(r.w))));
        }
#pragma unroll
        for (int off = 32; off > 0; off >>= 1)
            mx = fmaxf(mx, __shfl_down(mx, off, 64));
        if ((tid & 63) == 0) red[i & 1][tid >> 6] = mx;
        __syncthreads();
        float rmax = red[i & 1][0];
#pragma unroll
        for (int w = 1; w < 8; ++w) rmax = fmaxf(rmax, red[i & 1][w]);
        float scale = 127.0f / fmaxf(rmax, 1e-5f);
#pragma unroll
        for (int k = 0; k < 2; ++k) {
            char4 o;
            o.x = (signed char)(int)fminf(fmaxf(rintf(v[k].x * scale), -128.f), 127.f);
            o.y = (signed char)(int)fminf(fmaxf(rintf(v[k].y * scale), -128.f), 127.f);
            o.z = (signed char)(int)fminf(fmaxf(rintf(v[k].z * scale), -128.f), 127.f);
            o.w = (signed char)(int)fminf(fmaxf(rintf(v[k].w * scale), -128.f), 127.f);
            q[(size_t)t * 1024 + (k << 9) + tid] = o;
        }
        if (tid == 0) dq[t] = 1.0f / scale;
        // slide window
#pragma unroll
        for (int k = 0; k < 2; ++k) { pv[k] = cu[k]; cu[k] = nx[k]; nx[k] = pf[k]; }
    }
}

// int8 x ternary GEMM: C[m,n] = (sum_k A[m,k]*B[n,k]) * rowdq[m] * sc[slot]
// Block tile 128 x NT, 4 waves 2x2; wave tile 64 x NT/2.
// Double-buffered global_load_lds staging, one barrier per K-iter.
// XCD-aware remap: xcd = id&7 gets a fixed slice of 2^RLOG n-tiles so each
// XCD's L2 holds <=512KB of weights -> staging loads hit L2, not HBM.
// Global-side chunk swizzle keeps fragment ds_reads conflict-free (r2).
template<int NT, int RLOG>
__global__ __launch_bounds__(256) void gemm_i8(const int8_t* __restrict__ A,
                                               const int8_t* __restrict__ Bm,
                                               float* __restrict__ C,
                                               const float* __restrict__ rowdq,
                                               const float* __restrict__ sc, int slot,
                                               int N, int K) {
    constexpr int BPW = NT / 64;   // B-tiles staged per wave
    constexpr int WNT = NT / 32;   // n-tiles per wave
    constexpr int BB  = NT * 64;   // B bytes per LDS buffer
    __shared__ __align__(16) int8_t Alds[2][8192];
    __shared__ __align__(16) int8_t Blds[2][BB];
    const int tid  = threadIdx.x;
    const int lane = tid & 63;
    const int wave = tid >> 6;

    const int id  = blockIdx.y * gridDim.x + blockIdx.x;
    const int xcd = id & 7;
    const int s   = id >> 3;
    const int nb  = (xcd << RLOG) + (s & ((1 << RLOG) - 1));
    const int mb  = s >> RLOG;
    const int mbase = mb << 7;
    const int nbase = nb * NT;

    const int wm4 = (wave >> 1) << 2;   // first of 4 m-tiles
    const int wn0 = (wave & 1) * WNT;   // first of WNT n-tiles

    // staging: lane l -> row r_l, swizzled 16B chunk c_l of the 64B row
    const int r_l = lane >> 2;
    const int c_l = ((lane & 3) - ((lane >> 3) & 3)) & 3;
    const int at0 = wave * 2;           // 2 A-tiles per wave
    const int bt0 = wave * BPW;
    const int8_t* Ag0 = A + (size_t)(mbase + at0 * 16 + r_l) * K + c_l * 16;
    const int8_t* Ag1 = Ag0 + (size_t)16 * K;
    const int8_t* Bgb = Bm + (size_t)(nbase + bt0 * 16 + r_l) * K + c_l * 16;
    const int la0 = at0 << 10, la1 = la0 + 1024;
    const int lb0 = bt0 << 10;

    // fragment-read offset within a 1KB 16-row tile
    const int m_l = lane & 15, q_l = lane >> 4;
    const int fro = (4 * m_l + ((q_l + (m_l >> 1)) & 3)) << 4;

    v4i acc[4][WNT] = {};

    auto stage = [&](int buf, int ko) {
        GLOAD_LDS16(Ag0 + ko, &Alds[buf][la0]);
        GLOAD_LDS16(Ag1 + ko, &Alds[buf][la1]);
#pragma unroll
        for (int t = 0; t < BPW; ++t)
            GLOAD_LDS16(Bgb + (size_t)t * 16 * K + ko, &Blds[buf][lb0 + (t << 10)]);
    };
    auto compute = [&](int buf) {
        v4i af[4], bf[WNT];
#pragma unroll
        for (int i = 0; i < 4; ++i)
            af[i] = *reinterpret_cast<const v4i*>(&Alds[buf][fro + ((wm4 + i) << 10)]);
#pragma unroll
        for (int j = 0; j < WNT; ++j)
            bf[j] = *reinterpret_cast<const v4i*>(&Blds[buf][fro + ((wn0 + j) << 10)]);
#pragma unroll
        for (int i = 0; i < 4; ++i)
#pragma unroll
            for (int j = 0; j < WNT; ++j)
                acc[i][j] = __builtin_amdgcn_mfma_i32_16x16x64_i8(af[i], bf[j], acc[i][j], 0, 0, 0);
    };

    stage(0, 0);
    const int niter = K >> 6;
    for (int it = 0; it < niter; it += 2) {
        __syncthreads();
        if (it + 1 < niter) stage(1, (it + 1) << 6);
        compute(0);
        __syncthreads();
        if (it + 2 < niter) stage(0, (it + 2) << 6);
        compute(1);
    }

    const float wdq = sc[slot];
    const int quad = lane >> 4;
    const int col  = lane & 15;
#pragma unroll
    for (int i = 0; i < 4; ++i) {
#pragma unroll
        for (int r = 0; r < 4; ++r) {
            int m = mbase + ((wm4 + i) << 4) + (quad << 2) + r;  // C/D: row=(lane>>4)*4+reg
            float rs = rowdq[m] * wdq;
#pragma unroll
            for (int j = 0; j < WNT; ++j) {
                int n = nbase + ((wn0 + j) << 4) + col;          // C/D: col=lane&15
                C[(size_t)m * N + n] = (float)acc[i][j][r] * rs;
            }
        }
    }
}

// ---------------------------------------------------------------------------
extern "C" void kernel_launch(void* const* d_in, const int* in_sizes, int n_in,
                              void* d_out, int out_size, void* d_ws, size_t ws_size,
                              hipStream_t stream) {
    const float* x  = (const float*)d_in[0];  // [4,2048,1024]
    const float* w1 = (const float*)d_in[1];  // [4096,1024]
    const float* cw = (const float*)d_in[2];  // [4096,1,3]
    const float* cb = (const float*)d_in[3];  // [4096]
    const float* w2 = (const float*)d_in[4];  // [1024,4096]
    float* out = (float*)d_out;               // [4,2048,1024]
    char* ws = (char*)d_ws;

    // Workspace layout (16B-aligned); total ~185 MB
    double* part  = (double*)(ws + 0);          // 2048 doubles
    float*  sc    = (float*)(ws + 16384);       // {scale_w1, dq_w1, scale_w2, dq_w2}
    float*  dqx   = (float*)(ws + 16640);       // 8192 floats
    float*  dqh   = (float*)(ws + 49408);       // 8192 floats
    int8_t* qw1   = (int8_t*)(ws + 82176);      // 4 MB
    int8_t* qw2   = (int8_t*)(ws + 4276480);    // 4 MB
    int8_t* qx    = (int8_t*)(ws + 8470784);    // 8 MB
    int8_t* qh    = (int8_t*)(ws + 16859392);   // 32 MB
    float*  h     = (float*)(ws + 50413824);    // 128 MB

    absmean_partial<<<2048, 256, 0, stream>>>((const float4*)w1, (const float4*)w2, part);
    finalize_scales<<<1, 256, 0, stream>>>(part, sc);
    quant_w<<<8192, 256, 0, stream>>>((const float4*)w1, (const float4*)w2,
                                      (char4*)qw1, (char4*)qw2, sc);
    quant_x_kernel<<<NTOK, 256, 0, stream>>>((const float4*)x, (char4*)qx, dqx);

    // GEMM1: M=8192, N=4096, K=1024; 128x256 tiles -> grid (16,64), RLOG=1
    dim3 g1(DH / 256, NTOK / 128);
    gemm_i8<256, 1><<<g1, 256, 0, stream>>>(qx, qw1, h, dqx, sc, 1, DH, DM);

    conv_silu_quant<<<NTOK / CT, 512, 0, stream>>>((const float4*)h, (const float4*)cw,
                                                   (const float4*)cb, (char4*)qh, dqh);

    // GEMM2: M=8192, N=1024, K=4096; 128x128 tiles -> grid (8,64), RLOG=0
    dim3 g2(DM / 128, NTOK / 128);
    gemm_i8<128, 0><<<g2, 256, 0, stream>>>(qh, qw2, out, dqh, sc, 3, DM, DH);
}